// Round 2
// baseline (1226.490 us; speedup 1.0000x reference)
//
#include <hip/hip_runtime.h>
#include <hip/hip_bf16.h>
#include <math.h>

// Problem constants
#define B_    8
#define L_    2048
#define HID   768
#define KEY_  128
#define D2    384      // HIDDEN/2
#define NUV   1792     // 2*HID + 2*KEY
#define R_    (B_*L_)  // 16384 rows total
#define SCALE 0.08838834764831845f  // 128^-0.5

// ---------------------------------------------------------------------------
// Tiled f32 GEMM (for x@W_uv with silu epilogue, and gated@W_out)
// ---------------------------------------------------------------------------
#define BM 128
#define BN 128
#define BK 16

// EPI: 0 = none, 1 = silu on cols < siluLimit
template<int EPI>
__global__ __launch_bounds__(256) void gemm_tiled(
    const float* __restrict__ A, int lda,
    const float* __restrict__ B, int ldb,
    float* __restrict__ C, int ldc,
    int K, int siluLimit)
{
    __shared__ float As[BK][BM];
    __shared__ float Bs[BK][BN];

    const int t  = threadIdx.x;
    const int m0 = blockIdx.y * BM;
    const int n0 = blockIdx.x * BN;

    float acc[8][8];
#pragma unroll
    for (int i = 0; i < 8; ++i)
#pragma unroll
        for (int j = 0; j < 8; ++j) acc[i][j] = 0.0f;

    const int tr = t >> 4;   // 0..15
    const int tc = t & 15;   // 0..15

    for (int k0 = 0; k0 < K; k0 += BK) {
        // stage A tile (BM x BK), transposed into As[kk][r]
#pragma unroll
        for (int i = 0; i < 2; ++i) {
            int idx = t + i * 256;          // 512 float4 slots = 128*16 floats
            int r   = idx >> 2;
            int kk  = (idx & 3) << 2;
            const float4 v = *(const float4*)(A + (long long)(m0 + r) * lda + k0 + kk);
            As[kk + 0][r] = v.x; As[kk + 1][r] = v.y;
            As[kk + 2][r] = v.z; As[kk + 3][r] = v.w;
        }
        // stage B tile (BK x BN), coalesced float4
#pragma unroll
        for (int i = 0; i < 2; ++i) {
            int idx = t + i * 256;
            int kk  = idx >> 5;
            int c   = (idx & 31) << 2;
            *(float4*)&Bs[kk][c] = *(const float4*)(B + (long long)(k0 + kk) * ldb + n0 + c);
        }
        __syncthreads();

#pragma unroll
        for (int kk = 0; kk < BK; ++kk) {
            float4 a0 = *(const float4*)&As[kk][tr * 4];
            float4 a1 = *(const float4*)&As[kk][64 + tr * 4];
            float4 b0 = *(const float4*)&Bs[kk][tc * 4];
            float4 b1 = *(const float4*)&Bs[kk][64 + tc * 4];
            float av[8] = {a0.x, a0.y, a0.z, a0.w, a1.x, a1.y, a1.z, a1.w};
            float bv[8] = {b0.x, b0.y, b0.z, b0.w, b1.x, b1.y, b1.z, b1.w};
#pragma unroll
            for (int i = 0; i < 8; ++i)
#pragma unroll
                for (int j = 0; j < 8; ++j)
                    acc[i][j] = fmaf(av[i], bv[j], acc[i][j]);
        }
        __syncthreads();
    }

#pragma unroll
    for (int i = 0; i < 8; ++i) {
        int rloc = (i < 4) ? (tr * 4 + i) : (64 + tr * 4 + (i - 4));
        long long r = m0 + rloc;
#pragma unroll
        for (int h = 0; h < 2; ++h) {
            int cbase = n0 + h * 64 + tc * 4;
            float4 v;
            float* vp = &v.x;
#pragma unroll
            for (int j = 0; j < 4; ++j) {
                float x = acc[i][h * 4 + j];
                if (EPI == 1) {
                    if (cbase + j < siluLimit) x = x / (1.0f + __expf(-x));
                }
                vp[j] = x;
            }
            *(float4*)(C + r * ldc + cbase) = v;
        }
    }
}

// ---------------------------------------------------------------------------
// RoPE in place on q (cols 1536..1663) and k (cols 1664..1791) of uvqk
// ---------------------------------------------------------------------------
__global__ __launch_bounds__(128) void rope_qk(float* __restrict__ uvqk,
                                               const float* __restrict__ pos)
{
    int row = blockIdx.x;           // 0..16383
    int l   = row & (L_ - 1);
    int t   = threadIdx.x;          // 0..127
    int j   = t & 63;
    int isK = t >> 6;
    float* base = uvqk + (long long)row * NUV + 1536 + isK * 128;
    float s = pos[l * 256 + j];          // sin = pe[..., :64]
    float c = pos[l * 256 + 64 + j];     // cos = pe[..., 64:128]
    float x1 = base[j];
    float x2 = base[64 + j];
    base[j]      = x1 * c - x2 * s;
    base[64 + j] = x2 * c + x1 * s;
}

// ---------------------------------------------------------------------------
// Fused flash attention: S = q@k^T, online softmax, O = P@v, /l, gate by u.
// Writes gated result IN PLACE over u (uvqk cols 0..767).
// Block: 64 q-rows, 512 threads. KV tiles of 64.
// ---------------------------------------------------------------------------
#define QT 64
#define KT 64
#define QS_STRIDE 132
#define KS_STRIDE 132
#define P_STRIDE  68

__global__ __launch_bounds__(512, 2) void fused_attn(float* __restrict__ uvqk)
{
    __shared__ float qs[QT][QS_STRIDE];
    __shared__ float ks[KT][KS_STRIDE];
    __shared__ float Ps[QT][P_STRIDE];
    __shared__ float mrun[QT], lrun[QT], ratio_s[QT];

    const int t = threadIdx.x;
    const int qt = blockIdx.x;      // 0..31
    const int b  = blockIdx.y;      // 0..7
    const long long rowQ0 = (long long)b * L_ + (long long)qt * QT;
    const long long rowB0 = (long long)b * L_;

    // stage q tile (64 x 128)
#pragma unroll
    for (int i = 0; i < 4; ++i) {
        int idx = i * 512 + t;
        int r = idx >> 5, c4 = (idx & 31) << 2;
        float4 v = *(const float4*)(uvqk + (rowQ0 + r) * NUV + 1536 + c4);
        *(float4*)&qs[r][c4] = v;
    }
    if (t < QT) { mrun[t] = -3.0e38f; lrun[t] = 0.0f; }

    // PV mapping: rows rg*8..+7, cols cg*12..+11
    const int cg = t & 63;
    const int rg = t >> 6;
    float acc[8][12];
#pragma unroll
    for (int i = 0; i < 8; ++i)
#pragma unroll
        for (int j = 0; j < 12; ++j) acc[i][j] = 0.0f;

    // QK mapping: rows {ra, ra+32}, cols {cq + 16*ci}
    const int ra = t >> 4;   // 0..31
    const int cq = t & 15;   // 0..15

    for (int j = 0; j < L_ / KT; ++j) {
        // stage k tile (64 x 128)
#pragma unroll
        for (int i = 0; i < 4; ++i) {
            int idx = i * 512 + t;
            int r = idx >> 5, c4 = (idx & 31) << 2;
            float4 v = *(const float4*)(uvqk + (rowB0 + j * KT + r) * NUV + 1664 + c4);
            *(float4*)&ks[r][c4] = v;
        }
        __syncthreads();   // (A) ks/qs ready; prev PV done (all waves passed here)

        // ---- S = q@k^T : 2 rows x 4 cols per thread ----
        float s0[4] = {0.f, 0.f, 0.f, 0.f};
        float s1[4] = {0.f, 0.f, 0.f, 0.f};
#pragma unroll 8
        for (int d4 = 0; d4 < 32; ++d4) {
            float4 q0 = *(const float4*)&qs[ra][d4 * 4];
            float4 q1 = *(const float4*)&qs[ra + 32][d4 * 4];
#pragma unroll
            for (int ci = 0; ci < 4; ++ci) {
                float4 kv = *(const float4*)&ks[cq + 16 * ci][d4 * 4];
                s0[ci] = fmaf(q0.x, kv.x, fmaf(q0.y, kv.y, fmaf(q0.z, kv.z, fmaf(q0.w, kv.w, s0[ci]))));
                s1[ci] = fmaf(q1.x, kv.x, fmaf(q1.y, kv.y, fmaf(q1.z, kv.z, fmaf(q1.w, kv.w, s1[ci]))));
            }
        }

        // ---- online softmax stats (rows owned by 16-lane groups) ----
        float mx0 = fmaxf(fmaxf(s0[0], s0[1]), fmaxf(s0[2], s0[3]));
        float mx1 = fmaxf(fmaxf(s1[0], s1[1]), fmaxf(s1[2], s1[3]));
#pragma unroll
        for (int off = 8; off >= 1; off >>= 1) {
            mx0 = fmaxf(mx0, __shfl_xor(mx0, off));
            mx1 = fmaxf(mx1, __shfl_xor(mx1, off));
        }
        float mo0 = mrun[ra], mo1 = mrun[ra + 32];
        float mn0 = fmaxf(mo0, mx0), mn1 = fmaxf(mo1, mx1);

        float p0[4], p1[4];
        float ps0 = 0.f, ps1 = 0.f;
#pragma unroll
        for (int ci = 0; ci < 4; ++ci) {
            p0[ci] = __expf(SCALE * (s0[ci] - mn0)); ps0 += p0[ci];
            p1[ci] = __expf(SCALE * (s1[ci] - mn1)); ps1 += p1[ci];
        }
#pragma unroll
        for (int off = 8; off >= 1; off >>= 1) {
            ps0 += __shfl_xor(ps0, off);
            ps1 += __shfl_xor(ps1, off);
        }
        if (cq == 0) {
            float r0 = __expf(SCALE * (mo0 - mn0));
            float r1 = __expf(SCALE * (mo1 - mn1));
            ratio_s[ra]      = r0;
            ratio_s[ra + 32] = r1;
            lrun[ra]      = lrun[ra] * r0 + ps0;
            lrun[ra + 32] = lrun[ra + 32] * r1 + ps1;
            mrun[ra]      = mn0;
            mrun[ra + 32] = mn1;
        }
#pragma unroll
        for (int ci = 0; ci < 4; ++ci) {
            Ps[ra][cq + 16 * ci]      = p0[ci];
            Ps[ra + 32][cq + 16 * ci] = p1[ci];
        }
        __syncthreads();   // (B) P, ratio ready for PV

        // ---- PV: acc = acc*ratio + P @ v ----
#pragma unroll
        for (int i = 0; i < 8; ++i) {
            float f = ratio_s[rg * 8 + i];
#pragma unroll
            for (int jj = 0; jj < 12; ++jj) acc[i][jj] *= f;
        }
        const float* vbase = uvqk + (rowB0 + j * KT) * NUV + 768 + cg * 12;
        float4 va0 = *(const float4*)(vbase);
        float4 va1 = *(const float4*)(vbase + 4);
        float4 va2 = *(const float4*)(vbase + 8);
        for (int kk = 0; kk < KT; ++kk) {
            float4 nb0, nb1, nb2;
            if (kk + 1 < KT) {
                const float* p = vbase + (long long)(kk + 1) * NUV;
                nb0 = *(const float4*)(p);
                nb1 = *(const float4*)(p + 4);
                nb2 = *(const float4*)(p + 8);
            }
#pragma unroll
            for (int i = 0; i < 8; ++i) {
                float p = Ps[rg * 8 + i][kk];
                acc[i][0]  = fmaf(p, va0.x, acc[i][0]);
                acc[i][1]  = fmaf(p, va0.y, acc[i][1]);
                acc[i][2]  = fmaf(p, va0.z, acc[i][2]);
                acc[i][3]  = fmaf(p, va0.w, acc[i][3]);
                acc[i][4]  = fmaf(p, va1.x, acc[i][4]);
                acc[i][5]  = fmaf(p, va1.y, acc[i][5]);
                acc[i][6]  = fmaf(p, va1.z, acc[i][6]);
                acc[i][7]  = fmaf(p, va1.w, acc[i][7]);
                acc[i][8]  = fmaf(p, va2.x, acc[i][8]);
                acc[i][9]  = fmaf(p, va2.y, acc[i][9]);
                acc[i][10] = fmaf(p, va2.z, acc[i][10]);
                acc[i][11] = fmaf(p, va2.w, acc[i][11]);
            }
            if (kk + 1 < KT) { va0 = nb0; va1 = nb1; va2 = nb2; }
        }
        // no barrier needed: next-tile staging touches only ks (disjoint from Ps)
    }

    // ---- finalize: /l, gate by u, write gated over u (cols 0..767) ----
#pragma unroll
    for (int i = 0; i < 8; ++i) {
        int r = rg * 8 + i;
        float inv = 1.0f / lrun[r];
        float* ub = uvqk + (rowQ0 + r) * NUV + cg * 12;
        float4 u0 = *(const float4*)(ub);
        float4 u1 = *(const float4*)(ub + 4);
        float4 u2 = *(const float4*)(ub + 8);
        float4 o0 = make_float4(acc[i][0] * inv * u0.x,  acc[i][1] * inv * u0.y,
                                acc[i][2] * inv * u0.z,  acc[i][3] * inv * u0.w);
        float4 o1 = make_float4(acc[i][4] * inv * u1.x,  acc[i][5] * inv * u1.y,
                                acc[i][6] * inv * u1.z,  acc[i][7] * inv * u1.w);
        float4 o2 = make_float4(acc[i][8] * inv * u2.x,  acc[i][9] * inv * u2.y,
                                acc[i][10] * inv * u2.z, acc[i][11] * inv * u2.w);
        *(float4*)(ub)     = o0;
        *(float4*)(ub + 4) = o1;
        *(float4*)(ub + 8) = o2;
    }
}

extern "C" void kernel_launch(void* const* d_in, const int* in_sizes, int n_in,
                              void* d_out, int out_size, void* d_ws, size_t ws_size,
                              hipStream_t stream)
{
    const float* x    = (const float*)d_in[0];   // [8,2048,384]
    const float* pos  = (const float*)d_in[1];   // [1,2048,256]
    const float* Wuv  = (const float*)d_in[2];   // [384,1792]
    const float* Wout = (const float*)d_in[3];   // [768,384]
    float* out = (float*)d_out;                  // [8,2048,384] f32

    float* uvqk = (float*)d_ws;                  // [16384][1792] f32
    size_t need = (size_t)R_ * NUV * 4;          // 117.4 MB
    if (ws_size < need) return;                  // leaves output zero -> visible failure

    // 1) uvqk = x @ W_uv, silu on u|v columns [0,1536)
    gemm_tiled<1><<<dim3(NUV / BN, R_ / BM), dim3(256), 0, stream>>>(
        x, D2, Wuv, NUV, uvqk, NUV, D2, 1536);

    // 2) RoPE on q,k in place
    rope_qk<<<dim3(R_), dim3(128), 0, stream>>>(uvqk, pos);

    // 3) fused attention + gate; writes gated over u (cols 0..767)
    fused_attn<<<dim3(L_ / QT, B_), dim3(512), 0, stream>>>(uvqk);

    // 4) out = gated @ W_out
    gemm_tiled<0><<<dim3(D2 / BN, R_ / BM), dim3(256), 0, stream>>>(
        uvqk, NUV, Wout, D2, out, D2, HID, 0);
}

// Round 3
// 723.884 us; speedup vs baseline: 1.6943x; 1.6943x over previous
//
#include <hip/hip_runtime.h>
#include <hip/hip_bf16.h>
#include <math.h>

// Problem constants
#define B_    8
#define L_    2048
#define HID   768
#define KEY_  128
#define D2    384      // HIDDEN/2
#define NUV   1792     // 2*HID + 2*KEY
#define R_    (B_*L_)  // 16384 rows total
#define SCALE 0.08838834764831845f  // 128^-0.5

typedef __attribute__((ext_vector_type(8))) short bf16x8;
typedef __attribute__((ext_vector_type(4))) float f32x4;
typedef unsigned int   uint32;
typedef unsigned short ushort16;

// f32 -> bf16 round-to-nearest-even (finite inputs)
static __device__ __forceinline__ uint32 bfr(float x) {
    uint32 u = __float_as_uint(x);
    return (u + 0x7FFFu + ((u >> 16) & 1u)) >> 16;
}
static __device__ __forceinline__ uint32 pk2(float lo, float hi) {
    return bfr(lo) | (bfr(hi) << 16);
}

// ---------------------------------------------------------------------------
// Tiled f32 GEMM (x@W_uv with silu epilogue; gated@W_out) — unchanged, known good
// ---------------------------------------------------------------------------
#define BM 128
#define BN 128
#define BK 16

template<int EPI>
__global__ __launch_bounds__(256) void gemm_tiled(
    const float* __restrict__ A, int lda,
    const float* __restrict__ B, int ldb,
    float* __restrict__ C, int ldc,
    int K, int siluLimit)
{
    __shared__ float As[BK][BM];
    __shared__ float Bs[BK][BN];

    const int t  = threadIdx.x;
    const int m0 = blockIdx.y * BM;
    const int n0 = blockIdx.x * BN;

    float acc[8][8];
#pragma unroll
    for (int i = 0; i < 8; ++i)
#pragma unroll
        for (int j = 0; j < 8; ++j) acc[i][j] = 0.0f;

    const int tr = t >> 4;
    const int tc = t & 15;

    for (int k0 = 0; k0 < K; k0 += BK) {
#pragma unroll
        for (int i = 0; i < 2; ++i) {
            int idx = t + i * 256;
            int r   = idx >> 2;
            int kk  = (idx & 3) << 2;
            const float4 v = *(const float4*)(A + (long long)(m0 + r) * lda + k0 + kk);
            As[kk + 0][r] = v.x; As[kk + 1][r] = v.y;
            As[kk + 2][r] = v.z; As[kk + 3][r] = v.w;
        }
#pragma unroll
        for (int i = 0; i < 2; ++i) {
            int idx = t + i * 256;
            int kk  = idx >> 5;
            int c   = (idx & 31) << 2;
            *(float4*)&Bs[kk][c] = *(const float4*)(B + (long long)(k0 + kk) * ldb + n0 + c);
        }
        __syncthreads();

#pragma unroll
        for (int kk = 0; kk < BK; ++kk) {
            float4 a0 = *(const float4*)&As[kk][tr * 4];
            float4 a1 = *(const float4*)&As[kk][64 + tr * 4];
            float4 b0 = *(const float4*)&Bs[kk][tc * 4];
            float4 b1 = *(const float4*)&Bs[kk][64 + tc * 4];
            float av[8] = {a0.x, a0.y, a0.z, a0.w, a1.x, a1.y, a1.z, a1.w};
            float bv[8] = {b0.x, b0.y, b0.z, b0.w, b1.x, b1.y, b1.z, b1.w};
#pragma unroll
            for (int i = 0; i < 8; ++i)
#pragma unroll
                for (int j = 0; j < 8; ++j)
                    acc[i][j] = fmaf(av[i], bv[j], acc[i][j]);
        }
        __syncthreads();
    }

#pragma unroll
    for (int i = 0; i < 8; ++i) {
        int rloc = (i < 4) ? (tr * 4 + i) : (64 + tr * 4 + (i - 4));
        long long r = m0 + rloc;
#pragma unroll
        for (int h = 0; h < 2; ++h) {
            int cbase = n0 + h * 64 + tc * 4;
            float4 v;
            float* vp = &v.x;
#pragma unroll
            for (int j = 0; j < 4; ++j) {
                float x = acc[i][h * 4 + j];
                if (EPI == 1) {
                    if (cbase + j < siluLimit) x = x / (1.0f + __expf(-x));
                }
                vp[j] = x;
            }
            *(float4*)(C + r * ldc + cbase) = v;
        }
    }
}

// ---------------------------------------------------------------------------
// RoPE in place on q (cols 1536..1663) and k (cols 1664..1791) of uvqk
// ---------------------------------------------------------------------------
__global__ __launch_bounds__(128) void rope_qk(float* __restrict__ uvqk,
                                               const float* __restrict__ pos)
{
    int row = blockIdx.x;
    int l   = row & (L_ - 1);
    int t   = threadIdx.x;
    int j   = t & 63;
    int isK = t >> 6;
    float* base = uvqk + (long long)row * NUV + 1536 + isK * 128;
    float s = pos[l * 256 + j];
    float c = pos[l * 256 + 64 + j];
    float x1 = base[j];
    float x2 = base[64 + j];
    base[j]      = x1 * c - x2 * s;
    base[64 + j] = x2 * c + x1 * s;
}

// ---------------------------------------------------------------------------
// MFMA flash attention: S=q@k^T (bf16 MFMA), online softmax (f32),
// O=P@v (bf16 MFMA), /l, gate by u IN PLACE over u (uvqk cols 0..767).
// Block: 32 Q-rows, 512 threads (8 waves). KV tiles of 64 keys.
//   QK: wave w -> S-tile (rw=w&1, cw=w>>1), 16x16, K=128 (4 MFMA).
//   PV: wave w -> output cols w*96..+96 (2 row-tiles x 6 col-tiles, 24 MFMA).
// ---------------------------------------------------------------------------
__global__ __launch_bounds__(512) void fused_attn_mfma(float* __restrict__ uvqk)
{
    __shared__ ushort16 Kb[64][136];   // K-tile bf16, row stride 272B (16B-aligned b128, 2-way banks)
    __shared__ ushort16 Vt[768][68];   // V-tile transposed bf16 [vcol][key], stride 136B (b64-aligned, cf reads)
    __shared__ float    Ps[32][66];    // S-tile f32
    __shared__ ushort16 Pb[32][72];    // P bf16, stride 144B (16B-aligned b128)
    __shared__ float    mrun[32], lrun[32], ratio_s[32];

    const int t  = threadIdx.x;
    const int w  = t >> 6;       // wave 0..7
    const int l  = t & 63;
    const int g  = l >> 4;       // 0..3
    const int li = l & 15;

    const long long rowQ0 = (long long)blockIdx.y * L_ + (long long)blockIdx.x * 32;
    const long long rowB0 = (long long)blockIdx.y * L_;

    const int rw = w & 1;        // QK row-tile of this wave
    const int cw = w >> 1;       // QK col-tile (0..3)

    // ---- Q A-fragments in registers (once) ----
    bf16x8 qf[4];
    {
        const float* qrow = uvqk + (rowQ0 + rw * 16 + li) * NUV + 1536;
#pragma unroll
        for (int ks = 0; ks < 4; ++ks) {
            float4 a = *(const float4*)(qrow + ks * 32 + g * 8);
            float4 b = *(const float4*)(qrow + ks * 32 + g * 8 + 4);
            union { bf16x8 v; uint32 u[4]; } uu;
            uu.u[0] = pk2(a.x, a.y); uu.u[1] = pk2(a.z, a.w);
            uu.u[2] = pk2(b.x, b.y); uu.u[3] = pk2(b.z, b.w);
            qf[ks] = uu.v;
        }
    }
    if (t < 32) { mrun[t] = -3.0e38f; lrun[t] = 0.0f; }

    f32x4 o[2][6];
#pragma unroll
    for (int rt = 0; rt < 2; ++rt)
#pragma unroll
        for (int ct = 0; ct < 6; ++ct)
            o[rt][ct] = (f32x4){0.f, 0.f, 0.f, 0.f};

    for (int jt = 0; jt < L_ / 64; ++jt) {
        // ---- stage K tile (64x128 f32 -> bf16) ----
#pragma unroll
        for (int i = 0; i < 4; ++i) {
            int idx = i * 512 + t;
            int r   = idx >> 5;
            int c4  = (idx & 31) * 4;
            float4 v = *(const float4*)(uvqk + (rowB0 + jt * 64 + r) * NUV + 1664 + c4);
            uint2 p; p.x = pk2(v.x, v.y); p.y = pk2(v.z, v.w);
            *(uint2*)&Kb[r][c4] = p;
        }
        // ---- stage V tile transposed (64x768 f32 -> Vt[768][68] bf16) ----
#pragma unroll
        for (int i = 0; i < 12; ++i) {
            int id = i * 512 + t;
            int kp = id / 192;          // key pair 0..31
            int c4 = id - kp * 192;     // col group 0..191
            const float* vb = uvqk + (rowB0 + jt * 64 + 2 * kp) * NUV + 768 + c4 * 4;
            float4 a = *(const float4*)(vb);
            float4 b = *(const float4*)(vb + NUV);
            *(uint32*)&Vt[c4 * 4 + 0][2 * kp] = pk2(a.x, b.x);
            *(uint32*)&Vt[c4 * 4 + 1][2 * kp] = pk2(a.y, b.y);
            *(uint32*)&Vt[c4 * 4 + 2][2 * kp] = pk2(a.z, b.z);
            *(uint32*)&Vt[c4 * 4 + 3][2 * kp] = pk2(a.w, b.w);
        }
        __syncthreads();   // (A) Kb, Vt ready; prev-iter consumers done

        // ---- QK: one 16x16 S-tile per wave ----
        {
            f32x4 s = {0.f, 0.f, 0.f, 0.f};
#pragma unroll
            for (int ks = 0; ks < 4; ++ks) {
                bf16x8 kf = *(const bf16x8*)&Kb[cw * 16 + li][ks * 32 + g * 8];
                s = __builtin_amdgcn_mfma_f32_16x16x32_bf16(qf[ks], kf, s, 0, 0, 0);
            }
#pragma unroll
            for (int r = 0; r < 4; ++r)
                Ps[rw * 16 + g * 4 + r][cw * 16 + li] = s[r];
        }
        __syncthreads();   // (B) Ps ready

        // ---- online softmax: 16 lanes per row, 4 cols each ----
        {
            int row = t >> 4;
            float x0 = Ps[row][li], x1 = Ps[row][li + 16];
            float x2 = Ps[row][li + 32], x3 = Ps[row][li + 48];
            float mx = fmaxf(fmaxf(x0, x1), fmaxf(x2, x3));
#pragma unroll
            for (int off = 8; off >= 1; off >>= 1) mx = fmaxf(mx, __shfl_xor(mx, off));
            float mo = mrun[row];
            float mn = fmaxf(mo, mx);
            float p0 = __expf(SCALE * (x0 - mn)), p1 = __expf(SCALE * (x1 - mn));
            float p2 = __expf(SCALE * (x2 - mn)), p3 = __expf(SCALE * (x3 - mn));
            float ps = p0 + p1 + p2 + p3;
#pragma unroll
            for (int off = 8; off >= 1; off >>= 1) ps += __shfl_xor(ps, off);
            if (li == 0) {
                float rt_ = __expf(SCALE * (mo - mn));
                ratio_s[row] = rt_;
                lrun[row] = lrun[row] * rt_ + ps;
                mrun[row] = mn;
            }
            Pb[row][li]      = (ushort16)bfr(p0);
            Pb[row][li + 16] = (ushort16)bfr(p1);
            Pb[row][li + 32] = (ushort16)bfr(p2);
            Pb[row][li + 48] = (ushort16)bfr(p3);
        }
        __syncthreads();   // (C) Pb, ratio ready

        // ---- PV: rescale acc, then P@V over this wave's 96 cols ----
        {
            float rr[2][4];
#pragma unroll
            for (int rt = 0; rt < 2; ++rt)
#pragma unroll
                for (int r = 0; r < 4; ++r)
                    rr[rt][r] = ratio_s[rt * 16 + g * 4 + r];
#pragma unroll
            for (int rt = 0; rt < 2; ++rt)
#pragma unroll
                for (int ct = 0; ct < 6; ++ct)
#pragma unroll
                    for (int r = 0; r < 4; ++r)
                        o[rt][ct][r] *= rr[rt][r];
#pragma unroll
            for (int ks = 0; ks < 2; ++ks) {
                bf16x8 pa0 = *(const bf16x8*)&Pb[li][ks * 32 + g * 8];
                bf16x8 pa1 = *(const bf16x8*)&Pb[16 + li][ks * 32 + g * 8];
#pragma unroll
                for (int ct = 0; ct < 6; ++ct) {
                    int vc = w * 96 + ct * 16 + li;
                    union { bf16x8 v; uint2 q[2]; } uu;
                    uu.q[0] = *(const uint2*)&Vt[vc][ks * 32 + g * 8];
                    uu.q[1] = *(const uint2*)&Vt[vc][ks * 32 + g * 8 + 4];
                    o[0][ct] = __builtin_amdgcn_mfma_f32_16x16x32_bf16(pa0, uu.v, o[0][ct], 0, 0, 0);
                    o[1][ct] = __builtin_amdgcn_mfma_f32_16x16x32_bf16(pa1, uu.v, o[1][ct], 0, 0, 0);
                }
            }
        }
        __syncthreads();   // (D) PV done -> next staging may overwrite
    }

    // ---- finalize: /l, gate by u, write over u cols ----
    {
        float inv[2][4];
#pragma unroll
        for (int rt = 0; rt < 2; ++rt)
#pragma unroll
            for (int r = 0; r < 4; ++r)
                inv[rt][r] = 1.0f / lrun[rt * 16 + g * 4 + r];
#pragma unroll
        for (int rt = 0; rt < 2; ++rt) {
#pragma unroll
            for (int r = 0; r < 4; ++r) {
                float* ub = uvqk + (rowQ0 + rt * 16 + g * 4 + r) * NUV;
#pragma unroll
                for (int ct = 0; ct < 6; ++ct) {
                    int col = w * 96 + ct * 16 + li;
                    float uval = ub[col];
                    ub[col] = o[rt][ct][r] * inv[rt][r] * uval;
                }
            }
        }
    }
}

extern "C" void kernel_launch(void* const* d_in, const int* in_sizes, int n_in,
                              void* d_out, int out_size, void* d_ws, size_t ws_size,
                              hipStream_t stream)
{
    const float* x    = (const float*)d_in[0];   // [8,2048,384]
    const float* pos  = (const float*)d_in[1];   // [1,2048,256]
    const float* Wuv  = (const float*)d_in[2];   // [384,1792]
    const float* Wout = (const float*)d_in[3];   // [768,384]
    float* out = (float*)d_out;                  // [8,2048,384] f32

    float* uvqk = (float*)d_ws;                  // [16384][1792] f32
    size_t need = (size_t)R_ * NUV * 4;          // 117.4 MB
    if (ws_size < need) return;

    // 1) uvqk = x @ W_uv, silu on u|v columns [0,1536)
    gemm_tiled<1><<<dim3(NUV / BN, R_ / BM), dim3(256), 0, stream>>>(
        x, D2, Wuv, NUV, uvqk, NUV, D2, 1536);

    // 2) RoPE on q,k in place
    rope_qk<<<dim3(R_), dim3(128), 0, stream>>>(uvqk, pos);

    // 3) fused MFMA attention + gate; writes gated over u (cols 0..767)
    fused_attn_mfma<<<dim3(L_ / 32, B_), dim3(512), 0, stream>>>(uvqk);

    // 4) out = gated @ W_out
    gemm_tiled<0><<<dim3(D2 / BN, R_ / BM), dim3(256), 0, stream>>>(
        uvqk, NUV, Wout, D2, out, D2, HID, 0);
}

// Round 4
// 661.769 us; speedup vs baseline: 1.8534x; 1.0939x over previous
//
#include <hip/hip_runtime.h>
#include <hip/hip_bf16.h>
#include <math.h>

// Problem constants
#define B_    8
#define L_    2048
#define HID   768
#define D2    384      // HIDDEN/2
#define NUV   1792     // GEMM1 output logical cols
#define NUQ   1024     // slim uvqk: u(0..767) | q(768..895) | k(896..1023)
#define R_    16384
#define SCALE 0.08838834764831845f  // 128^-0.5

typedef __attribute__((ext_vector_type(8))) short bf16x8;
typedef __attribute__((ext_vector_type(4))) float f32x4;
typedef unsigned int uint32;

static __device__ __forceinline__ uint32 bfr(float x) {
    uint32 u = __float_as_uint(x);
    return (u + 0x7FFFu + ((u >> 16) & 1u)) >> 16;
}
static __device__ __forceinline__ uint32 pk2(float lo, float hi) {
    return bfr(lo) | (bfr(hi) << 16);
}
static __device__ __forceinline__ float silu_f(float x) { return x / (1.0f + __expf(-x)); }

// ---------------------------------------------------------------------------
// Tiled f32 GEMM.
// EPI 0: plain C write (lda/ldb/ldc as given)
// EPI 3: GAU mode for x@W_uv: u cols -> silu -> uvqk[.][0..767];
//        v cols -> silu -> bf16 TRANSPOSED into vT[b][c][l];
//        q/k cols -> uvqk[.][768..1023]. ldc = NUQ.
// ---------------------------------------------------------------------------
#define BM 128
#define BN 128
#define BK 16

template<int EPI>
__global__ __launch_bounds__(256) void gemm_tiled(
    const float* __restrict__ A, int lda,
    const float* __restrict__ B, int ldb,
    float* __restrict__ C, int ldc,
    unsigned short* __restrict__ vT,
    int K)
{
    __shared__ float As[BK][BM];
    __shared__ float Bs[BK][BN];

    const int t  = threadIdx.x;
    const int m0 = blockIdx.y * BM;
    const int n0 = blockIdx.x * BN;

    float acc[8][8];
#pragma unroll
    for (int i = 0; i < 8; ++i)
#pragma unroll
        for (int j = 0; j < 8; ++j) acc[i][j] = 0.0f;

    const int tr = t >> 4;
    const int tc = t & 15;

    for (int k0 = 0; k0 < K; k0 += BK) {
#pragma unroll
        for (int i = 0; i < 2; ++i) {
            int idx = t + i * 256;
            int r   = idx >> 2;
            int kk  = (idx & 3) << 2;
            const float4 v = *(const float4*)(A + (long long)(m0 + r) * lda + k0 + kk);
            As[kk + 0][r] = v.x; As[kk + 1][r] = v.y;
            As[kk + 2][r] = v.z; As[kk + 3][r] = v.w;
        }
#pragma unroll
        for (int i = 0; i < 2; ++i) {
            int idx = t + i * 256;
            int kk  = idx >> 5;
            int c   = (idx & 31) << 2;
            *(float4*)&Bs[kk][c] = *(const float4*)(B + (long long)(k0 + kk) * ldb + n0 + c);
        }
        __syncthreads();

#pragma unroll
        for (int kk = 0; kk < BK; ++kk) {
            float4 a0 = *(const float4*)&As[kk][tr * 4];
            float4 a1 = *(const float4*)&As[kk][64 + tr * 4];
            float4 b0 = *(const float4*)&Bs[kk][tc * 4];
            float4 b1 = *(const float4*)&Bs[kk][64 + tc * 4];
            float av[8] = {a0.x, a0.y, a0.z, a0.w, a1.x, a1.y, a1.z, a1.w};
            float bv[8] = {b0.x, b0.y, b0.z, b0.w, b1.x, b1.y, b1.z, b1.w};
#pragma unroll
            for (int i = 0; i < 8; ++i)
#pragma unroll
                for (int j = 0; j < 8; ++j)
                    acc[i][j] = fmaf(av[i], bv[j], acc[i][j]);
        }
        __syncthreads();
    }

    if (EPI == 0) {
#pragma unroll
        for (int i = 0; i < 8; ++i) {
            int rloc = (i < 4) ? (tr * 4 + i) : (64 + tr * 4 + (i - 4));
            long long r = m0 + rloc;
#pragma unroll
            for (int h = 0; h < 2; ++h) {
                int cbase = n0 + h * 64 + tc * 4;
                float4 v = make_float4(acc[i][h*4+0], acc[i][h*4+1], acc[i][h*4+2], acc[i][h*4+3]);
                *(float4*)(C + r * ldc + cbase) = v;
            }
        }
    } else {
        // GAU epilogue; each 128-col block is purely one of {u, v, qk}
        if (n0 >= 768 && n0 < 1536) {
            // v: silu -> bf16, transposed pairs along rows into vT[b][c-768][l]
#pragma unroll
            for (int p = 0; p < 4; ++p) {
                int i0 = p * 2;
                int rloc = (p < 2) ? (tr * 4 + i0) : (64 + tr * 4 + (i0 - 4));
                long long r = m0 + rloc;           // rows r, r+1 (r even)
                int bb = (int)(r >> 11);
                int ll = (int)(r & 2047);
#pragma unroll
                for (int h = 0; h < 2; ++h) {
#pragma unroll
                    for (int j = 0; j < 4; ++j) {
                        int cv = n0 + h * 64 + tc * 4 + j - 768;
                        uint32 wv = pk2(silu_f(acc[i0][h*4+j]), silu_f(acc[i0+1][h*4+j]));
                        *(uint32*)&vT[((size_t)bb * 768 + cv) * 2048 + ll] = wv;
                    }
                }
            }
        } else {
            const bool doSilu = (n0 < 768);
            const int coff = (n0 >= 1536) ? 768 : 0;   // q/k shift into slim layout
#pragma unroll
            for (int i = 0; i < 8; ++i) {
                int rloc = (i < 4) ? (tr * 4 + i) : (64 + tr * 4 + (i - 4));
                long long r = m0 + rloc;
#pragma unroll
                for (int h = 0; h < 2; ++h) {
                    int cbase = n0 + h * 64 + tc * 4 - coff;
                    float4 v;
                    float* vp = &v.x;
#pragma unroll
                    for (int j = 0; j < 4; ++j) {
                        float x = acc[i][h*4+j];
                        vp[j] = doSilu ? silu_f(x) : x;
                    }
                    *(float4*)(C + r * (long long)NUQ + cbase) = v;
                }
            }
        }
    }
}

// ---------------------------------------------------------------------------
// RoPE in place on q (cols 768..895) and k (cols 896..1023) of slim uvqk
// ---------------------------------------------------------------------------
__global__ __launch_bounds__(128) void rope_qk(float* __restrict__ uvqk,
                                               const float* __restrict__ pos)
{
    int row = blockIdx.x;
    int l   = row & (L_ - 1);
    int t   = threadIdx.x;
    int j   = t & 63;
    int isK = t >> 6;
    float* base = uvqk + (long long)row * NUQ + 768 + isK * 128;
    float s = pos[l * 256 + j];
    float c = pos[l * 256 + 64 + j];
    float x1 = base[j];
    float x2 = base[64 + j];
    base[j]      = x1 * c - x2 * s;
    base[64 + j] = x2 * c + x1 * s;
}

// ---------------------------------------------------------------------------
// MFMA flash attention v2.
//  - K staged in LDS row-major [64][128] bf16 with XOR swizzle byte^=((row&7)<<4)
//  - P staged in LDS [32][64] bf16, same swizzle
//  - V read DIRECTLY from global vT (bf16, [b][col][key]) as coalesced 16B frags
//  - 3 barriers/tile; gate by u written in place over uvqk cols 0..767
// Block: 512 threads (8 waves), 32 Q-rows; KV tile 64. Grid: 512 (b = blk&7 -> XCD pin)
// ---------------------------------------------------------------------------
__global__ __launch_bounds__(512, 4) void fused_attn2(
    float* __restrict__ uvqk, const unsigned short* __restrict__ vT)
{
    __shared__ unsigned char KbB[64 * 256];   // bf16 [64][128], swizzled
    __shared__ float Ps[32][68];              // S-tile f32, padded
    __shared__ unsigned char PbB[32 * 128];   // P bf16 [32][64], swizzled
    __shared__ float mrun[32], lrun[32], ratio_s[32];

    const int t  = threadIdx.x;
    const int w  = t >> 6;
    const int l  = t & 63;
    const int g  = l >> 4;
    const int li = l & 15;

    const int b  = blockIdx.x & 7;
    const int qt = blockIdx.x >> 3;
    const long long rowQ0 = (long long)b * L_ + (long long)qt * 32;
    const long long rowB0 = (long long)b * L_;

    const int rw = w & 1;    // QK S row-tile
    const int cw = w >> 1;   // QK S col-tile

    // ---- Q A-fragments (once) ----
    bf16x8 qf[4];
    {
        const float* qrow = uvqk + (rowQ0 + rw * 16 + li) * NUQ + 768;
#pragma unroll
        for (int ks = 0; ks < 4; ++ks) {
            float4 a = *(const float4*)(qrow + ks * 32 + g * 8);
            float4 c = *(const float4*)(qrow + ks * 32 + g * 8 + 4);
            union { bf16x8 v; uint32 u[4]; } uu;
            uu.u[0] = pk2(a.x, a.y); uu.u[1] = pk2(a.z, a.w);
            uu.u[2] = pk2(c.x, c.y); uu.u[3] = pk2(c.z, c.w);
            qf[ks] = uu.v;
        }
    }
    if (t < 32) { mrun[t] = -3.0e38f; lrun[t] = 0.0f; }

    f32x4 o[2][6];
#pragma unroll
    for (int rt = 0; rt < 2; ++rt)
#pragma unroll
        for (int ct = 0; ct < 6; ++ct)
            o[rt][ct] = (f32x4){0.f, 0.f, 0.f, 0.f};

    // per-lane V base: vT[b][w*96 + li][.] + g*8
    const unsigned short* vrow = vT + ((size_t)b * 768 + w * 96 + li) * 2048 + g * 8;

    for (int jt = 0; jt < L_ / 64; ++jt) {
        // ---- stage K tile (64x128 f32 -> bf16, swizzled; conflict-free 8B writes) ----
#pragma unroll
        for (int it = 0; it < 4; ++it) {
            int idx = it * 512 + t;
            int r   = idx >> 5;
            int c4  = idx & 31;
            float4 v = *(const float4*)(uvqk + (rowB0 + jt * 64 + r) * NUQ + 896 + c4 * 4);
            uint2 p; p.x = pk2(v.x, v.y); p.y = pk2(v.z, v.w);
            *(uint2*)&KbB[r * 256 + ((c4 * 8) ^ ((r & 7) << 4))] = p;
        }
        __syncthreads();   // (A) Kb ready

        // ---- QK: one 16x16 S-tile per wave, K=128 ----
        {
            f32x4 s = {0.f, 0.f, 0.f, 0.f};
            const int krow = cw * 16 + li;
#pragma unroll
            for (int ks = 0; ks < 4; ++ks) {
                bf16x8 kf = *(const bf16x8*)&KbB[krow * 256 + ((ks * 64 + g * 16) ^ ((li & 7) << 4))];
                s = __builtin_amdgcn_mfma_f32_16x16x32_bf16(qf[ks], kf, s, 0, 0, 0);
            }
#pragma unroll
            for (int r = 0; r < 4; ++r)
                Ps[rw * 16 + g * 4 + r][cw * 16 + li] = s[r];
        }
        __syncthreads();   // (B) Ps ready

        // ---- online softmax: 16 lanes/row, 4 consecutive cols each ----
        {
            int row = t >> 4;
            float4 x4 = *(const float4*)&Ps[row][li * 4];
            float mx = fmaxf(fmaxf(x4.x, x4.y), fmaxf(x4.z, x4.w));
#pragma unroll
            for (int off = 8; off >= 1; off >>= 1) mx = fmaxf(mx, __shfl_xor(mx, off));
            float mo = mrun[row];
            float mn = fmaxf(mo, mx);
            float p0 = __expf(SCALE * (x4.x - mn)), p1 = __expf(SCALE * (x4.y - mn));
            float p2 = __expf(SCALE * (x4.z - mn)), p3 = __expf(SCALE * (x4.w - mn));
            float ps = p0 + p1 + p2 + p3;
#pragma unroll
            for (int off = 8; off >= 1; off >>= 1) ps += __shfl_xor(ps, off);
            if (li == 0) {
                float rt_ = __expf(SCALE * (mo - mn));
                ratio_s[row] = rt_;
                lrun[row] = lrun[row] * rt_ + ps;
                mrun[row] = mn;
            }
            uint2 pw; pw.x = pk2(p0, p1); pw.y = pk2(p2, p3);
            *(uint2*)&PbB[row * 128 + ((li * 8) ^ ((row & 7) << 4))] = pw;
        }
        __syncthreads();   // (C) Pb, ratio ready

        // ---- PV: rescale, then P@V with V frags from global (2-deep pipeline) ----
        {
            float rr[2][4];
#pragma unroll
            for (int rt = 0; rt < 2; ++rt)
#pragma unroll
                for (int r = 0; r < 4; ++r)
                    rr[rt][r] = ratio_s[rt * 16 + g * 4 + r];
#pragma unroll
            for (int rt = 0; rt < 2; ++rt)
#pragma unroll
                for (int ct = 0; ct < 6; ++ct)
#pragma unroll
                    for (int r = 0; r < 4; ++r)
                        o[rt][ct][r] *= rr[rt][r];

            bf16x8 pa[2][2];
#pragma unroll
            for (int rt = 0; rt < 2; ++rt)
#pragma unroll
                for (int ks = 0; ks < 2; ++ks)
                    pa[rt][ks] = *(const bf16x8*)&PbB[(rt * 16 + li) * 128 +
                                                     ((ks * 64 + g * 16) ^ ((li & 7) << 4))];

            const unsigned short* vj = vrow + jt * 64;
            union U16 { uint4 u; bf16x8 bv; };
            U16 va, vb;
            va.u = *(const uint4*)(vj);
            vb.u = *(const uint4*)(vj + 32);
#pragma unroll
            for (int ct = 0; ct < 6; ++ct) {
                U16 na, nb;
                if (ct < 5) {
                    na.u = *(const uint4*)(vj + (size_t)(ct + 1) * 32768);
                    nb.u = *(const uint4*)(vj + (size_t)(ct + 1) * 32768 + 32);
                } else { na = va; nb = vb; }
                o[0][ct] = __builtin_amdgcn_mfma_f32_16x16x32_bf16(pa[0][0], va.bv, o[0][ct], 0, 0, 0);
                o[0][ct] = __builtin_amdgcn_mfma_f32_16x16x32_bf16(pa[0][1], vb.bv, o[0][ct], 0, 0, 0);
                o[1][ct] = __builtin_amdgcn_mfma_f32_16x16x32_bf16(pa[1][0], va.bv, o[1][ct], 0, 0, 0);
                o[1][ct] = __builtin_amdgcn_mfma_f32_16x16x32_bf16(pa[1][1], vb.bv, o[1][ct], 0, 0, 0);
                va = na; vb = nb;
            }
        }
        // no 4th barrier needed: next K-stage touches only KbB (QK readers done 2 barriers ago)
    }

    // ---- finalize: /l, gate by u, write over u cols ----
    {
        float inv[2][4];
#pragma unroll
        for (int rt = 0; rt < 2; ++rt)
#pragma unroll
            for (int r = 0; r < 4; ++r)
                inv[rt][r] = 1.0f / lrun[rt * 16 + g * 4 + r];
#pragma unroll
        for (int rt = 0; rt < 2; ++rt) {
#pragma unroll
            for (int r = 0; r < 4; ++r) {
                float* ub = uvqk + (rowQ0 + rt * 16 + g * 4 + r) * NUQ;
#pragma unroll
                for (int ct = 0; ct < 6; ++ct) {
                    int col = w * 96 + ct * 16 + li;
                    ub[col] = o[rt][ct][r] * inv[rt][r] * ub[col];
                }
            }
        }
    }
}

extern "C" void kernel_launch(void* const* d_in, const int* in_sizes, int n_in,
                              void* d_out, int out_size, void* d_ws, size_t ws_size,
                              hipStream_t stream)
{
    const float* x    = (const float*)d_in[0];   // [8,2048,384]
    const float* pos  = (const float*)d_in[1];   // [1,2048,256]
    const float* Wuv  = (const float*)d_in[2];   // [384,1792]
    const float* Wout = (const float*)d_in[3];   // [768,384]
    float* out = (float*)d_out;                  // [8,2048,384] f32

    float* uvqk = (float*)d_ws;                                  // [16384][1024] f32 (67.1 MB)
    unsigned short* vT = (unsigned short*)(uvqk + (size_t)R_ * NUQ); // [8][768][2048] bf16 (25.2 MB)
    size_t need = (size_t)R_ * NUQ * 4 + (size_t)B_ * HID * L_ * 2;  // 92.3 MB
    if (ws_size < need) return;

    // 1) GEMM1: u->silu->uvqk, v->silu->bf16->vT (transposed), q/k->uvqk
    gemm_tiled<3><<<dim3(NUV / BN, R_ / BM), dim3(256), 0, stream>>>(
        x, D2, Wuv, NUV, uvqk, NUQ, vT, D2);

    // 2) RoPE on q,k in place
    rope_qk<<<dim3(R_), dim3(128), 0, stream>>>(uvqk, pos);

    // 3) fused MFMA attention + gate (writes gated over u cols)
    fused_attn2<<<dim3(512), dim3(512), 0, stream>>>(uvqk, vT);

    // 4) out = gated @ W_out
    gemm_tiled<0><<<dim3(D2 / BN, R_ / BM), dim3(256), 0, stream>>>(
        uvqk, NUQ, Wout, D2, out, D2, nullptr, HID);
}

// Round 5
// 388.246 us; speedup vs baseline: 3.1591x; 1.7045x over previous
//
#include <hip/hip_runtime.h>
#include <hip/hip_bf16.h>
#include <math.h>

#define B_    8
#define L_    2048
#define HID   768
#define D2    384
#define NUV   1792
#define R_    16384
#define SCALE 0.08838834764831845f  // 128^-0.5

typedef __attribute__((ext_vector_type(8))) short bf16x8;
typedef __attribute__((ext_vector_type(4))) float f32x4;
typedef unsigned int uint32;
typedef unsigned short ushort;

static __device__ __forceinline__ uint32 bfr(float x) {
    uint32 u = __float_as_uint(x);
    return (u + 0x7FFFu + ((u >> 16) & 1u)) >> 16;
}
static __device__ __forceinline__ uint32 pk2(float lo, float hi) {
    return bfr(lo) | (bfr(hi) << 16);
}
static __device__ __forceinline__ float bf2f(ushort u) {
    return __uint_as_float(((uint32)u) << 16);
}
static __device__ __forceinline__ float silu_f(float x) { return x / (1.0f + __expf(-x)); }

// ---------------------------------------------------------------------------
// Weight pre-transform: Thi/Tlo[n][k] = bf16 hi/lo split of W[k][n]
// ---------------------------------------------------------------------------
__global__ __launch_bounds__(256) void conv_w(const float* __restrict__ W,
                                              ushort* __restrict__ Thi,
                                              ushort* __restrict__ Tlo,
                                              int K, int N)
{
    int idx = blockIdx.x * 256 + threadIdx.x;
    if (idx >= K * N) return;
    int n = idx / K, k = idx - n * K;
    float x = W[(size_t)k * N + n];
    uint32 h = bfr(x);
    float hf = __uint_as_float(h << 16);
    Thi[idx] = (ushort)h;
    Tlo[idx] = (ushort)bfr(x - hf);
}

// ---------------------------------------------------------------------------
// Split-bf16 MFMA GEMM: C = A(f32,[M][K]) @ B(f32,[K][N]) via 3-pass hi/lo.
// B supplied pre-transposed+split: BThi/BTlo [N][K] bf16.
// Block 512 thr (8 waves), tile 128x128, BK=64. Wave = 32 rows x 64 cols.
// EPI 0: C f32 (ldc)     EPI 1: GAU GEMM1 epilogue (u/v/qk by n0)
// ---------------------------------------------------------------------------
template<int EPI>
__global__ __launch_bounds__(512, 4) void gemm_mfma(
    const float* __restrict__ A, int lda,
    const ushort* __restrict__ BThi, const ushort* __restrict__ BTlo, int ldbt,
    float* __restrict__ C, int ldc,
    ushort* __restrict__ qk, ushort* __restrict__ vT, int K)
{
    __shared__ unsigned char As[128 * 256];   // [row][hi 128B | lo 128B], XOR swizzle
    __shared__ unsigned char Bs[128 * 256];   // [col][hi 128B | lo 128B], XOR swizzle

    const int t  = threadIdx.x;
    const int w  = t >> 6;
    const int l  = t & 63;
    const int g  = l >> 4;
    const int li = l & 15;
    const int wr = w >> 1;    // 0..3 row-group (32 rows)
    const int wc = w & 1;     // 0..1 col-half (64 cols)
    const int m0 = blockIdx.y * 128;
    const int n0 = blockIdx.x * 128;

    f32x4 acc[2][4];
#pragma unroll
    for (int i = 0; i < 2; ++i)
#pragma unroll
        for (int j = 0; j < 4; ++j) acc[i][j] = (f32x4){0.f, 0.f, 0.f, 0.f};

    for (int k0 = 0; k0 < K; k0 += 64) {
        // ---- stage A: 128x64 f32 -> hi/lo bf16 ----
#pragma unroll
        for (int i = 0; i < 4; ++i) {
            int idx = t + i * 512;
            int r   = idx >> 4;
            int c16 = idx & 15;
            float4 v = *(const float4*)(A + (long long)(m0 + r) * lda + k0 + c16 * 4);
            uint2 h; h.x = pk2(v.x, v.y); h.y = pk2(v.z, v.w);
            float hx = __uint_as_float((h.x & 0xFFFFu) << 16), hy = __uint_as_float(h.x & 0xFFFF0000u);
            float hz = __uint_as_float((h.y & 0xFFFFu) << 16), hw = __uint_as_float(h.y & 0xFFFF0000u);
            uint2 lo; lo.x = pk2(v.x - hx, v.y - hy); lo.y = pk2(v.z - hz, v.w - hw);
            int sw = (c16 * 8) ^ ((r & 7) << 4);
            *(uint2*)&As[r * 256 + sw]       = h;
            *(uint2*)&As[r * 256 + 128 + sw] = lo;
        }
        // ---- stage B: copy pre-split hi/lo rows ----
#pragma unroll
        for (int i = 0; i < 8; ++i) {
            int idx = t + i * 512;
            int c   = idx >> 5;
            int s8  = idx & 31;
            const ushort* src = (s8 < 16)
                ? (BThi + (long long)(n0 + c) * ldbt + k0 + s8 * 4)
                : (BTlo + (long long)(n0 + c) * ldbt + k0 + (s8 - 16) * 4);
            *(uint2*)&Bs[c * 256 + ((s8 * 8) ^ ((c & 7) << 4))] = *(const uint2*)src;
        }
        __syncthreads();

        // ---- compute: 2x4 frags x 2 ks x 3 passes ----
#pragma unroll
        for (int ks = 0; ks < 2; ++ks) {
            bf16x8 ah[2], al[2], bh[4], bl[4];
#pragma unroll
            for (int mi = 0; mi < 2; ++mi) {
                int row = wr * 32 + mi * 16 + li;
                int off = (ks * 64 + g * 16) ^ ((row & 7) << 4);
                ah[mi] = *(const bf16x8*)&As[row * 256 + off];
                al[mi] = *(const bf16x8*)&As[row * 256 + 128 + off];
            }
#pragma unroll
            for (int ni = 0; ni < 4; ++ni) {
                int col = wc * 64 + ni * 16 + li;
                int off = (ks * 64 + g * 16) ^ ((col & 7) << 4);
                bh[ni] = *(const bf16x8*)&Bs[col * 256 + off];
                bl[ni] = *(const bf16x8*)&Bs[col * 256 + 128 + off];
            }
#pragma unroll
            for (int mi = 0; mi < 2; ++mi)
#pragma unroll
                for (int ni = 0; ni < 4; ++ni) {
                    acc[mi][ni] = __builtin_amdgcn_mfma_f32_16x16x32_bf16(ah[mi], bh[ni], acc[mi][ni], 0, 0, 0);
                    acc[mi][ni] = __builtin_amdgcn_mfma_f32_16x16x32_bf16(ah[mi], bl[ni], acc[mi][ni], 0, 0, 0);
                    acc[mi][ni] = __builtin_amdgcn_mfma_f32_16x16x32_bf16(al[mi], bh[ni], acc[mi][ni], 0, 0, 0);
                }
        }
        __syncthreads();
    }

    // ---- epilogue ----
    if (EPI == 0) {
#pragma unroll
        for (int mi = 0; mi < 2; ++mi)
#pragma unroll
            for (int ni = 0; ni < 4; ++ni) {
                int col = n0 + wc * 64 + ni * 16 + li;
#pragma unroll
                for (int r = 0; r < 4; ++r) {
                    int row = m0 + wr * 32 + mi * 16 + g * 4 + r;
                    C[(long long)row * ldc + col] = acc[mi][ni][r];
                }
            }
    } else {
        if (n0 < 768) {
            // u: silu -> f32 u_buf (ldc = 768)
#pragma unroll
            for (int mi = 0; mi < 2; ++mi)
#pragma unroll
                for (int ni = 0; ni < 4; ++ni) {
                    int col = n0 + wc * 64 + ni * 16 + li;
#pragma unroll
                    for (int r = 0; r < 4; ++r) {
                        int row = m0 + wr * 32 + mi * 16 + g * 4 + r;
                        C[(long long)row * 768 + col] = silu_f(acc[mi][ni][r]);
                    }
                }
        } else if (n0 < 1536) {
            // v: silu -> bf16 transposed vT[b][cv][l], row-pairs packed
            int bb = m0 >> 11;
            int llb = (m0 & 2047) + wr * 32 + g * 4;
#pragma unroll
            for (int mi = 0; mi < 2; ++mi) {
                int ll = llb + mi * 16;
#pragma unroll
                for (int ni = 0; ni < 4; ++ni) {
                    int cv = n0 + wc * 64 + ni * 16 + li - 768;
                    ushort* vb = vT + ((size_t)bb * 768 + cv) * 2048 + ll;
                    *(uint32*)(vb)     = pk2(silu_f(acc[mi][ni][0]), silu_f(acc[mi][ni][1]));
                    *(uint32*)(vb + 2) = pk2(silu_f(acc[mi][ni][2]), silu_f(acc[mi][ni][3]));
                }
            }
        } else {
            // q/k: bf16 -> qk[row][qcol], q cols 0..127, k cols 128..255
#pragma unroll
            for (int mi = 0; mi < 2; ++mi)
#pragma unroll
                for (int ni = 0; ni < 4; ++ni) {
                    int qcol = n0 + wc * 64 + ni * 16 + li - 1536;
#pragma unroll
                    for (int r = 0; r < 4; ++r) {
                        int row = m0 + wr * 32 + mi * 16 + g * 4 + r;
                        qk[(size_t)row * 256 + qcol] = (ushort)bfr(acc[mi][ni][r]);
                    }
                }
        }
    }
}

// ---------------------------------------------------------------------------
// RoPE in place on bf16 qk buffer (q cols 0..127, k cols 128..255)
// ---------------------------------------------------------------------------
__global__ __launch_bounds__(128) void rope_bf(ushort* __restrict__ qk,
                                               const float* __restrict__ pos)
{
    int row = blockIdx.x;
    int lpos = row & (L_ - 1);
    int t = threadIdx.x;
    int j = t & 63;
    int isK = t >> 6;
    ushort* base = qk + (size_t)row * 256 + isK * 128;
    float s = pos[lpos * 256 + j];
    float c = pos[lpos * 256 + 64 + j];
    float x1 = bf2f(base[j]);
    float x2 = bf2f(base[64 + j]);
    base[j]      = (ushort)bfr(x1 * c - x2 * s);
    base[64 + j] = (ushort)bfr(x2 * c + x1 * s);
}

// ---------------------------------------------------------------------------
// MFMA flash attention (round-4 structure, bf16 Q/K source).
// Gates u_buf (f32 [16384][768]) IN PLACE.
// ---------------------------------------------------------------------------
__global__ __launch_bounds__(512, 4) void fused_attn2(
    float* __restrict__ u_buf, const ushort* __restrict__ qk,
    const ushort* __restrict__ vT)
{
    __shared__ unsigned char KbB[64 * 256];
    __shared__ float Ps[32][68];
    __shared__ unsigned char PbB[32 * 128];
    __shared__ float mrun[32], lrun[32], ratio_s[32];

    const int t  = threadIdx.x;
    const int w  = t >> 6;
    const int l  = t & 63;
    const int g  = l >> 4;
    const int li = l & 15;

    const int b  = blockIdx.x & 7;
    const int qt = blockIdx.x >> 3;
    const long long rowQ0 = (long long)b * L_ + (long long)qt * 32;
    const long long rowB0 = (long long)b * L_;

    const int rw = w & 1;
    const int cw = w >> 1;

    // Q A-fragments from bf16 qk
    bf16x8 qf[4];
    {
        const ushort* qrow = qk + (rowQ0 + rw * 16 + li) * 256;
#pragma unroll
        for (int ks = 0; ks < 4; ++ks)
            qf[ks] = *(const bf16x8*)&qrow[ks * 32 + g * 8];
    }
    if (t < 32) { mrun[t] = -3.0e38f; lrun[t] = 0.0f; }

    f32x4 o[2][6];
#pragma unroll
    for (int rt = 0; rt < 2; ++rt)
#pragma unroll
        for (int ct = 0; ct < 6; ++ct)
            o[rt][ct] = (f32x4){0.f, 0.f, 0.f, 0.f};

    const ushort* vrow = vT + ((size_t)b * 768 + w * 96 + li) * 2048 + g * 8;

    for (int jt = 0; jt < L_ / 64; ++jt) {
        // stage K tile from bf16 qk cols 128..255
#pragma unroll
        for (int it = 0; it < 2; ++it) {
            int idx = it * 512 + t;
            int r   = idx >> 4;
            int s16 = idx & 15;
            uint4 v = *(const uint4*)&qk[(rowB0 + jt * 64 + r) * 256 + 128 + s16 * 8];
            *(uint4*)&KbB[r * 256 + ((s16 * 16) ^ ((r & 7) << 4))] = v;
        }
        __syncthreads();   // (A)

        {
            f32x4 s = {0.f, 0.f, 0.f, 0.f};
            const int krow = cw * 16 + li;
#pragma unroll
            for (int ks = 0; ks < 4; ++ks) {
                bf16x8 kf = *(const bf16x8*)&KbB[krow * 256 + ((ks * 64 + g * 16) ^ ((li & 7) << 4))];
                s = __builtin_amdgcn_mfma_f32_16x16x32_bf16(qf[ks], kf, s, 0, 0, 0);
            }
#pragma unroll
            for (int r = 0; r < 4; ++r)
                Ps[rw * 16 + g * 4 + r][cw * 16 + li] = s[r];
        }
        __syncthreads();   // (B)

        {
            int row = t >> 4;
            float4 x4 = *(const float4*)&Ps[row][li * 4];
            float mx = fmaxf(fmaxf(x4.x, x4.y), fmaxf(x4.z, x4.w));
#pragma unroll
            for (int off = 8; off >= 1; off >>= 1) mx = fmaxf(mx, __shfl_xor(mx, off));
            float mo = mrun[row];
            float mn = fmaxf(mo, mx);
            float p0 = __expf(SCALE * (x4.x - mn)), p1 = __expf(SCALE * (x4.y - mn));
            float p2 = __expf(SCALE * (x4.z - mn)), p3 = __expf(SCALE * (x4.w - mn));
            float ps = p0 + p1 + p2 + p3;
#pragma unroll
            for (int off = 8; off >= 1; off >>= 1) ps += __shfl_xor(ps, off);
            if (li == 0) {
                float rt_ = __expf(SCALE * (mo - mn));
                ratio_s[row] = rt_;
                lrun[row] = lrun[row] * rt_ + ps;
                mrun[row] = mn;
            }
            uint2 pw; pw.x = pk2(p0, p1); pw.y = pk2(p2, p3);
            *(uint2*)&PbB[row * 128 + ((li * 8) ^ ((row & 7) << 4))] = pw;
        }
        __syncthreads();   // (C)

        {
            float rr[2][4];
#pragma unroll
            for (int rt = 0; rt < 2; ++rt)
#pragma unroll
                for (int r = 0; r < 4; ++r)
                    rr[rt][r] = ratio_s[rt * 16 + g * 4 + r];
#pragma unroll
            for (int rt = 0; rt < 2; ++rt)
#pragma unroll
                for (int ct = 0; ct < 6; ++ct)
#pragma unroll
                    for (int r = 0; r < 4; ++r)
                        o[rt][ct][r] *= rr[rt][r];

            bf16x8 pa[2][2];
#pragma unroll
            for (int rt = 0; rt < 2; ++rt)
#pragma unroll
                for (int ks = 0; ks < 2; ++ks)
                    pa[rt][ks] = *(const bf16x8*)&PbB[(rt * 16 + li) * 128 +
                                                     ((ks * 64 + g * 16) ^ ((li & 7) << 4))];

            const ushort* vj = vrow + jt * 64;
            union U16 { uint4 u; bf16x8 bv; };
            U16 va, vb;
            va.u = *(const uint4*)(vj);
            vb.u = *(const uint4*)(vj + 32);
#pragma unroll
            for (int ct = 0; ct < 6; ++ct) {
                U16 na, nb;
                if (ct < 5) {
                    na.u = *(const uint4*)(vj + (size_t)(ct + 1) * 32768);
                    nb.u = *(const uint4*)(vj + (size_t)(ct + 1) * 32768 + 32);
                } else { na = va; nb = vb; }
                o[0][ct] = __builtin_amdgcn_mfma_f32_16x16x32_bf16(pa[0][0], va.bv, o[0][ct], 0, 0, 0);
                o[0][ct] = __builtin_amdgcn_mfma_f32_16x16x32_bf16(pa[0][1], vb.bv, o[0][ct], 0, 0, 0);
                o[1][ct] = __builtin_amdgcn_mfma_f32_16x16x32_bf16(pa[1][0], va.bv, o[1][ct], 0, 0, 0);
                o[1][ct] = __builtin_amdgcn_mfma_f32_16x16x32_bf16(pa[1][1], vb.bv, o[1][ct], 0, 0, 0);
                va = na; vb = nb;
            }
        }
    }

    // finalize: /l, gate u in place (f32)
    {
        float inv[2][4];
#pragma unroll
        for (int rt = 0; rt < 2; ++rt)
#pragma unroll
            for (int r = 0; r < 4; ++r)
                inv[rt][r] = 1.0f / lrun[rt * 16 + g * 4 + r];
#pragma unroll
        for (int rt = 0; rt < 2; ++rt) {
#pragma unroll
            for (int r = 0; r < 4; ++r) {
                float* ub = u_buf + (rowQ0 + rt * 16 + g * 4 + r) * 768;
#pragma unroll
                for (int ct = 0; ct < 6; ++ct) {
                    int col = w * 96 + ct * 16 + li;
                    ub[col] = o[rt][ct][r] * inv[rt][r] * ub[col];
                }
            }
        }
    }
}

extern "C" void kernel_launch(void* const* d_in, const int* in_sizes, int n_in,
                              void* d_out, int out_size, void* d_ws, size_t ws_size,
                              hipStream_t stream)
{
    const float* x    = (const float*)d_in[0];   // [8,2048,384]
    const float* pos  = (const float*)d_in[1];   // [1,2048,256]
    const float* Wuv  = (const float*)d_in[2];   // [384,1792]
    const float* Wout = (const float*)d_in[3];   // [768,384]
    float* out = (float*)d_out;                  // [8,2048,384] f32

    float*  u_buf = (float*)d_ws;                        // 16384*768 f32
    ushort* qk    = (ushort*)(u_buf + (size_t)R_ * HID); // 16384*256 bf16
    ushort* vT    = qk + (size_t)R_ * 256;               // 8*768*2048 bf16
    ushort* WuvThi  = vT + (size_t)B_ * HID * L_;        // 1792*384
    ushort* WuvTlo  = WuvThi + (size_t)NUV * D2;
    ushort* WoutThi = WuvTlo + (size_t)NUV * D2;         // 384*768
    ushort* WoutTlo = WoutThi + (size_t)D2 * HID;

    size_t need = ((size_t)R_ * HID) * 4 +
                  ((size_t)R_ * 256 + (size_t)B_ * HID * L_ +
                   2 * (size_t)NUV * D2 + 2 * (size_t)D2 * HID) * 2;
    if (ws_size < need) return;

    // 0) weight transpose + hi/lo split
    conv_w<<<dim3((D2 * NUV + 255) / 256), dim3(256), 0, stream>>>(Wuv, WuvThi, WuvTlo, D2, NUV);
    conv_w<<<dim3((HID * D2 + 255) / 256), dim3(256), 0, stream>>>(Wout, WoutThi, WoutTlo, HID, D2);

    // 1) GEMM1 (split-bf16 MFMA): u/v/qk epilogues
    gemm_mfma<1><<<dim3(NUV / 128, R_ / 128), dim3(512), 0, stream>>>(
        x, D2, WuvThi, WuvTlo, D2, u_buf, HID, qk, vT, D2);

    // 2) RoPE on bf16 q/k
    rope_bf<<<dim3(R_), dim3(128), 0, stream>>>(qk, pos);

    // 3) fused MFMA attention + gate (in-place on u_buf)
    fused_attn2<<<dim3(512), dim3(512), 0, stream>>>(u_buf, qk, vT);

    // 4) out = gated @ W_out (split-bf16 MFMA)
    gemm_mfma<0><<<dim3(D2 / 128, R_ / 128), dim3(512), 0, stream>>>(
        u_buf, HID, WoutThi, WoutTlo, HID, out, D2, nullptr, nullptr, HID);
}